// Round 1
// baseline (293.132 us; speedup 1.0000x reference)
//
#include <hip/hip_runtime.h>

// Problem constants (frozen by the reference)
#define NN 16
#define CC 64
#define HH 128
#define WW 128

// ---------------------------------------------------------------------------
// Kernel 0: transpose w3 (co, ci, 1, 5) -> wt[ci][k][co] so that for fixed
// (ci, k) the 4 consecutive co a thread needs form one float4.
// ---------------------------------------------------------------------------
__global__ __launch_bounds__(256) void transpose_w(const float* __restrict__ w3,
                                                   float* __restrict__ wt) {
    int idx = blockIdx.x * 256 + threadIdx.x;
    if (idx < CC * CC * 5) {
        int k  = idx % 5;
        int ci = (idx / 5) % CC;
        int co = idx / (5 * CC);
        wt[(ci * 5 + k) * CC + co] = w3[idx];
    }
}

// ---------------------------------------------------------------------------
// Kernel 1: t3 = 1x5 conv (64 -> 64 channels, padding 2 on W).
// One block per (n, h) row. x[n, :, h, :] staged in LDS (64 x 136 floats,
// data at offset +4 so all LDS float4 ops are 16B-aligned; zeros at the
// +-2 pad positions). Each thread computes a 4co x 8w register tile:
// per ci iteration: 4 aligned b128 LDS reads (x window w0-4..w0+11),
// 5 float4 global reads of L2-resident transposed weights, 160 FMAs.
// VALU-bound by design (~320 VALU cyc vs ~80 LDS cyc per ci).
// ---------------------------------------------------------------------------
__global__ __launch_bounds__(256) void conv1x5(const float* __restrict__ x,
                                               const float* __restrict__ wt,
                                               float* __restrict__ t3) {
    __shared__ float xs[CC][136];   // [ci][4 + w], w in [-4, 131]
    const int nh  = blockIdx.x;
    const int n   = nh >> 7;        // / HH
    const int h   = nh & (HH - 1);
    const int tid = threadIdx.x;

    // Stage x[n, ci, h, :] for all ci: 2048 float4, 8 per thread.
    const float* xbase = x + (((size_t)n * CC) * HH + h) * WW;
    #pragma unroll
    for (int i = 0; i < 8; ++i) {
        int idx = tid + i * 256;        // float4 index 0..2047
        int ci  = idx >> 5;             // 32 float4 per row
        int wq  = idx & 31;
        float4 v = *(const float4*)(xbase + (size_t)ci * (HH * WW) + wq * 4);
        *(float4*)&xs[ci][4 + wq * 4] = v;
    }
    // Zero pad: positions [0..3] (w=-4..-1) and [132..135] (w=128..131).
    for (int i = tid; i < CC * 8; i += 256) {
        int ci = i >> 3;
        int j  = i & 7;
        xs[ci][j < 4 ? j : 128 + j] = 0.f;
    }
    __syncthreads();

    const int co0 = (tid >> 4) * 4;       // 16 co-groups of 4
    const int w0  = (tid & 15) * 8;       // 16 w-groups of 8 (lanes coalesced in w)

    float acc[4][8];
    #pragma unroll
    for (int a = 0; a < 4; ++a)
        #pragma unroll
        for (int b = 0; b < 8; ++b) acc[a][b] = 0.f;

    for (int ci = 0; ci < CC; ++ci) {
        // x window: logical w in [w0-4, w0+11]  (xs index w0 .. w0+15, 32B aligned)
        float xv[16];
        #pragma unroll
        for (int q = 0; q < 4; ++q) {
            float4 v = *(const float4*)&xs[ci][w0 + q * 4];
            xv[q*4+0] = v.x; xv[q*4+1] = v.y; xv[q*4+2] = v.z; xv[q*4+3] = v.w;
        }
        float wv[4][5];
        #pragma unroll
        for (int k = 0; k < 5; ++k) {
            float4 v = *(const float4*)(wt + (ci * 5 + k) * CC + co0);
            wv[0][k] = v.x; wv[1][k] = v.y; wv[2][k] = v.z; wv[3][k] = v.w;
        }
        #pragma unroll
        for (int k = 0; k < 5; ++k)
            #pragma unroll
            for (int a = 0; a < 4; ++a)
                #pragma unroll
                for (int b = 0; b < 8; ++b)
                    // logical x index: w0 + b + k - 2  ->  xv[b + k + 2]
                    acc[a][b] = fmaf(wv[a][k], xv[b + k + 2], acc[a][b]);
    }

    #pragma unroll
    for (int a = 0; a < 4; ++a) {
        float* o = t3 + ((((size_t)n * CC) + co0 + a) * HH + h) * WW + w0;
        *(float4*)(o)     = make_float4(acc[a][0], acc[a][1], acc[a][2], acc[a][3]);
        *(float4*)(o + 4) = make_float4(acc[a][4], acc[a][5], acc[a][6], acc[a][7]);
    }
}

// ---------------------------------------------------------------------------
// Kernel 2: out = t7 * t3 where
//   t7[n,c,h,w] = sum_{j,i} w7[c,3j+i] * max(lhs(i), rhs(j,i))
//   lhs(i)   = x[n,c,h, w+2(i-1)]                    (0 if W-OOB)
//   rhs(j,i) = x[n,c,h+i-1, ((w-1)%W) + 2(j-1)]      (0 if H- or W-OOB)
// One thread per element; neighborhood reuse served by L1/L2.
// ---------------------------------------------------------------------------
__global__ __launch_bounds__(256) void combine(const float* __restrict__ x,
                                               const float* __restrict__ t3,
                                               const float* __restrict__ w7,
                                               float* __restrict__ out) {
    const int idx = blockIdx.x * 256 + threadIdx.x;
    const int w   = idx & (WW - 1);
    const int h   = (idx >> 7) & (HH - 1);
    const int nc  = idx >> 14;            // n*CC + c
    const int c   = nc & (CC - 1);
    const float* xb = x + (size_t)nc * (HH * WW);
    const int wr  = (w - 1) & (WW - 1);   // circular roll by SHIFT=1

    float lhs[3];
    #pragma unroll
    for (int i = 0; i < 3; ++i) {
        int wi = w + 2 * (i - 1);
        lhs[i] = ((unsigned)wi < WW) ? xb[h * WW + wi] : 0.f;
    }

    float acc = 0.f;
    #pragma unroll
    for (int j = 0; j < 3; ++j) {
        #pragma unroll
        for (int i = 0; i < 3; ++i) {
            int hh = h + i - 1;
            int wj = wr + 2 * (j - 1);
            float rhs = ((unsigned)hh < HH && (unsigned)wj < WW) ? xb[hh * WW + wj] : 0.f;
            acc = fmaf(w7[c * 9 + j * 3 + i], fmaxf(lhs[i], rhs), acc);
        }
    }
    out[idx] = acc * t3[idx];
}

extern "C" void kernel_launch(void* const* d_in, const int* in_sizes, int n_in,
                              void* d_out, int out_size, void* d_ws, size_t ws_size,
                              hipStream_t stream) {
    const float* x  = (const float*)d_in[0];
    const float* w3 = (const float*)d_in[1];
    const float* w7 = (const float*)d_in[2];
    float* out = (float*)d_out;

    // Workspace layout: t3 (64 MiB) then transposed weights (80 KiB).
    float* t3 = (float*)d_ws;
    float* wt = t3 + (size_t)NN * CC * HH * WW;

    transpose_w<<<(CC * CC * 5 + 255) / 256, 256, 0, stream>>>(w3, wt);
    conv1x5<<<NN * HH, 256, 0, stream>>>(x, wt, t3);
    combine<<<(NN * CC * HH * WW) / 256, 256, 0, stream>>>(x, t3, w7, out);
}

// Round 2
// 160.467 us; speedup vs baseline: 1.8267x; 1.8267x over previous
//
#include <hip/hip_runtime.h>

// Problem constants (frozen by the reference)
#define NN 16
#define CC 64
#define HH 128
#define WW 128

#define LDS_STRIDE 72   // bf16 elems per xsT row: 144 B = 16B-aligned, 2-way-bank-free

typedef __attribute__((ext_vector_type(8))) short short8;   // bf16x8 (4 VGPRs)
typedef __attribute__((ext_vector_type(4))) float floatx4;  // MFMA C/D

__device__ __forceinline__ short f2bf(float f) {
    // round-to-nearest-even float -> bf16 bits
    union { float f; unsigned u; } v; v.f = f;
    unsigned r = v.u + 0x7fffu + ((v.u >> 16) & 1u);
    return (short)(r >> 16);
}

// ---------------------------------------------------------------------------
// Kernel 0: w3 (co, ci, 1, 5) fp32 -> Abf[co][kk] bf16, kk = tap*64 + ci.
// K-order tap-major so any 8-aligned run of kk stays within one tap and spans
// 8 consecutive ci (matches one ds_read_b128 of the transposed x row).
// ---------------------------------------------------------------------------
__global__ __launch_bounds__(256) void prep_w(const float* __restrict__ w3,
                                              short* __restrict__ Abf) {
    int idx = blockIdx.x * 256 + threadIdx.x;
    if (idx < CC * CC * 5) {
        int tap = idx % 5;
        int ci  = (idx / 5) % CC;
        int co  = idx / (5 * CC);
        Abf[co * 320 + tap * 64 + ci] = f2bf(w3[idx]);
    }
}

// ---------------------------------------------------------------------------
// Kernel 1: t3 = 1x5 conv as bf16 MFMA GEMM. One block per (n,h) row:
// D[co 0..63][w 0..127] = sum_kk A[co][kk] * B[kk][w],  kk = tap*64+ci,
// B[kk][w] = x[ci][w + tap - 2] (zero-padded), staged transposed in LDS:
// xsT[wp = w+2][ci] bf16. Wave W owns co-tile W (16 co) x 8 w-tiles.
// Fragment layouts (guide-verified): A[m=lane&15][k=g*8+j], B[k=g*8+j][n=lane&15],
// D[row=g*4+r][col=lane&15], g = lane>>4.
// ---------------------------------------------------------------------------
__global__ __launch_bounds__(256) void conv_mfma(const float* __restrict__ x,
                                                 const short* __restrict__ Abf,
                                                 float* __restrict__ t3) {
    __shared__ short xsT[132 * LDS_STRIDE];
    const int nh  = blockIdx.x;
    const int n   = nh >> 7;
    const int h   = nh & (HH - 1);
    const int tid = threadIdx.x;

    // Stage x[n, :, h, :] transposed to xsT[w+2][ci] as bf16.
    const float* xbase = x + (((size_t)n * CC) * HH + h) * WW;
    #pragma unroll
    for (int i = 0; i < 8; ++i) {
        int idx = tid + i * 256;        // float4 index 0..2047
        int ci  = idx >> 5;
        int wq  = idx & 31;
        float4 v = *(const float4*)(xbase + (size_t)ci * (HH * WW) + wq * 4);
        int wp = wq * 4 + 2;
        xsT[(wp + 0) * LDS_STRIDE + ci] = f2bf(v.x);
        xsT[(wp + 1) * LDS_STRIDE + ci] = f2bf(v.y);
        xsT[(wp + 2) * LDS_STRIDE + ci] = f2bf(v.z);
        xsT[(wp + 3) * LDS_STRIDE + ci] = f2bf(v.w);
    }
    // Zero pad rows wp in {0,1,130,131} (w = -2,-1,128,129): one entry/thread.
    {
        int wpi = tid >> 6;                       // 0..3
        int wpz = (wpi < 2) ? wpi : 128 + wpi;    // 0,1,130,131
        int ci  = tid & 63;
        xsT[wpz * LDS_STRIDE + ci] = 0;
    }
    __syncthreads();

    const int W    = tid >> 6;       // wave id -> co-tile
    const int lane = tid & 63;
    const int lm   = lane & 15;
    const int g    = lane >> 4;

    floatx4 acc[8];                  // one 16x16 tile per w-tile
    #pragma unroll
    for (int nt = 0; nt < 8; ++nt) acc[nt] = (floatx4){0.f, 0.f, 0.f, 0.f};

    const short* arow = Abf + (W * 16 + lm) * 320;

    for (int ks = 0; ks < 10; ++ks) {
        const int kbase = ks * 32 + g * 8;       // this lane-group's first kk
        const int tap   = kbase >> 6;            // constant over the 8 kk
        const int cib   = kbase & 63;            // 8-aligned

        short8 a = *(const short8*)(arow + kbase);
        #pragma unroll
        for (int nt = 0; nt < 8; ++nt) {
            int wp = nt * 16 + lm + tap;         // (w + 2) + tap - 2
            short8 b = *(const short8*)&xsT[wp * LDS_STRIDE + cib];
            acc[nt] = __builtin_amdgcn_mfma_f32_16x16x32_bf16(a, b, acc[nt], 0, 0, 0);
        }
    }

    // Epilogue: D[row][col], co = W*16 + g*4 + r, w = nt*16 + lm.
    #pragma unroll
    for (int nt = 0; nt < 8; ++nt) {
        #pragma unroll
        for (int r = 0; r < 4; ++r) {
            int co = W * 16 + g * 4 + r;
            t3[(((size_t)n * CC + co) * HH + h) * WW + nt * 16 + lm] = acc[nt][r];
        }
    }
}

// ---------------------------------------------------------------------------
// Kernel 2: out = t7 * t3, 4 outputs per thread, float4 window loads.
//   t7[n,c,h,w] = sum_{j,i} w7[c,3j+i] * max(lhs(i), rhs(j,i))
//   lhs(i)   = x[n,c,h, w+2(i-1)]                 (0 if W-OOB)
//   rhs(j,i) = x[n,c,h+i-1, ((w-1)&127)+2(j-1)]   (0 if H/W-OOB)
// Window win[r][0..11] = x[h+r-1][w0-4 .. w0+7]; whole-float4 OOB zeroing is
// exact because spans align to the 4-grid. Only w==0 wraps (cols 125,127).
// ---------------------------------------------------------------------------
__global__ __launch_bounds__(256) void combine4(const float* __restrict__ x,
                                                const float* __restrict__ t3,
                                                const float* __restrict__ w7,
                                                float* __restrict__ out) {
    const int tid4 = blockIdx.x * 256 + threadIdx.x;
    const int flat = tid4 * 4;
    const int w0 = flat & (WW - 1);
    const int h  = (flat >> 7) & (HH - 1);
    const int nc = flat >> 14;
    const int c  = nc & (CC - 1);
    const float* xb = x + (size_t)nc * (HH * WW);

    float win[3][12];
    #pragma unroll
    for (int r = 0; r < 3; ++r) {
        int hh = h + r - 1;
        bool hok = (unsigned)hh < HH;
        #pragma unroll
        for (int q = 0; q < 3; ++q) {
            int cb = w0 - 4 + q * 4;
            float4 v = make_float4(0.f, 0.f, 0.f, 0.f);
            if (hok && (unsigned)cb < WW)
                v = *(const float4*)(xb + hh * WW + cb);
            win[r][q * 4 + 0] = v.x; win[r][q * 4 + 1] = v.y;
            win[r][q * 4 + 2] = v.z; win[r][q * 4 + 3] = v.w;
        }
    }
    // w==0 wrap: rhs cols 125, 127 (j=2 -> col 129 -> 0).
    float wrap0[3] = {0.f, 0.f, 0.f}, wrap1[3] = {0.f, 0.f, 0.f};
    if (w0 == 0) {
        #pragma unroll
        for (int r = 0; r < 3; ++r) {
            int hh = h + r - 1;
            if ((unsigned)hh < HH) {
                wrap0[r] = xb[hh * WW + 125];
                wrap1[r] = xb[hh * WW + 127];
            }
        }
    }
    float wc[9];
    #pragma unroll
    for (int t = 0; t < 9; ++t) wc[t] = w7[c * 9 + t];

    float4 t3v = *(const float4*)(t3 + flat);
    float res[4];
    #pragma unroll
    for (int e = 0; e < 4; ++e) {
        float acc = 0.f;
        #pragma unroll
        for (int j = 0; j < 3; ++j) {
            #pragma unroll
            for (int i = 0; i < 3; ++i) {
                float lhs = win[1][e + 2 * i + 2];        // col w+2(i-1)
                float rhs;
                if (e == 0 && w0 == 0)
                    rhs = (j == 0) ? wrap0[i] : ((j == 1) ? wrap1[i] : 0.f);
                else
                    rhs = win[i][e + 2 * j + 1];          // col w+2j-3
                acc = fmaf(wc[j * 3 + i], fmaxf(lhs, rhs), acc);
            }
        }
        res[e] = acc;
    }
    float4 o;
    o.x = res[0] * t3v.x; o.y = res[1] * t3v.y;
    o.z = res[2] * t3v.z; o.w = res[3] * t3v.w;
    *(float4*)(out + flat) = o;
}

extern "C" void kernel_launch(void* const* d_in, const int* in_sizes, int n_in,
                              void* d_out, int out_size, void* d_ws, size_t ws_size,
                              hipStream_t stream) {
    const float* x  = (const float*)d_in[0];
    const float* w3 = (const float*)d_in[1];
    const float* w7 = (const float*)d_in[2];
    float* out = (float*)d_out;

    // Workspace: t3 (64 MiB) then bf16 weights (40 KiB).
    float* t3  = (float*)d_ws;
    short* Abf = (short*)(t3 + (size_t)NN * CC * HH * WW);

    prep_w<<<(CC * CC * 5 + 255) / 256, 256, 0, stream>>>(w3, Abf);
    conv_mfma<<<NN * HH, 256, 0, stream>>>(x, Abf, t3);
    combine4<<<(NN * CC * HH * WW) / (4 * 256), 256, 0, stream>>>(x, t3, w7, out);
}

// Round 3
// 154.220 us; speedup vs baseline: 1.9007x; 1.0405x over previous
//
#include <hip/hip_runtime.h>

// Problem constants (frozen by the reference)
#define NN 16
#define CC 64
#define HH 128
#define WW 128

#define LDS_STRIDE 72   // bf16 elems per xsT row: 144 B = 16B-aligned, 2-way-bank-free
#define T3_STRIDE 132   // fp32 elems per t3s row: 528 B = 16B-aligned

typedef __attribute__((ext_vector_type(8))) short short8;   // bf16x8 (4 VGPRs)
typedef __attribute__((ext_vector_type(4))) float floatx4;  // MFMA C/D

__device__ __forceinline__ short f2bf(float f) {
    // round-to-nearest-even float -> bf16 bits
    union { float f; unsigned u; } v; v.f = f;
    unsigned r = v.u + 0x7fffu + ((v.u >> 16) & 1u);
    return (short)(r >> 16);
}

// ---------------------------------------------------------------------------
// Kernel 0: w3 (co, ci, 1, 5) fp32 -> Abf[co][kk] bf16, kk = tap*64 + ci.
// ---------------------------------------------------------------------------
__global__ __launch_bounds__(256) void prep_w(const float* __restrict__ w3,
                                              short* __restrict__ Abf) {
    int idx = blockIdx.x * 256 + threadIdx.x;
    if (idx < CC * CC * 5) {
        int tap = idx % 5;
        int ci  = (idx / 5) % CC;
        int co  = idx / (5 * CC);
        Abf[co * 320 + tap * 64 + ci] = f2bf(w3[idx]);
    }
}

// ---------------------------------------------------------------------------
// Fused kernel: one block per (n,h) row.
// Phase 1: stage x[n,:,h,:] transposed bf16 into xsT (as in R2's conv_mfma).
// Phase 2: MFMA GEMM D[co][w] = sum_{kk} A[co][kk] B[kk][w], kk = tap*64+ci.
// Phase 3: epilogue writes D into fp32 LDS t3s[co][w] (aliases dead xsT).
// Phase 4: combine: out = t3 * sum_{j,i} w7[c,3j+i]*max(lhs(i), rhs(j,i)),
//          lhs/rhs read from global x (rows h-1,h,h+1), t3 from LDS.
// ---------------------------------------------------------------------------
__global__ __launch_bounds__(256) void fused(const float* __restrict__ x,
                                             const short* __restrict__ Abf,
                                             const float* __restrict__ w7,
                                             float* __restrict__ out) {
    __shared__ __align__(16) char smem[CC * T3_STRIDE * 4];  // 33792 B
    short* xsT = (short*)smem;        // [132][LDS_STRIDE], phase 1-2
    float* t3s = (float*)smem;        // [CC][T3_STRIDE],  phase 3-4 (aliased)

    const int nh  = blockIdx.x;
    const int n   = nh >> 7;
    const int h   = nh & (HH - 1);
    const int tid = threadIdx.x;

    // ---- Phase 1: stage x row h, transposed, bf16 ----
    const float* xbase = x + (((size_t)n * CC) * HH + h) * WW;
    #pragma unroll
    for (int i = 0; i < 8; ++i) {
        int idx = tid + i * 256;        // float4 index 0..2047
        int ci  = idx >> 5;
        int wq  = idx & 31;
        float4 v = *(const float4*)(xbase + (size_t)ci * (HH * WW) + wq * 4);
        int wp = wq * 4 + 2;
        xsT[(wp + 0) * LDS_STRIDE + ci] = f2bf(v.x);
        xsT[(wp + 1) * LDS_STRIDE + ci] = f2bf(v.y);
        xsT[(wp + 2) * LDS_STRIDE + ci] = f2bf(v.z);
        xsT[(wp + 3) * LDS_STRIDE + ci] = f2bf(v.w);
    }
    {   // zero pad rows wp in {0,1,130,131}
        int wpi = tid >> 6;
        int wpz = (wpi < 2) ? wpi : 128 + wpi;
        int ci  = tid & 63;
        xsT[wpz * LDS_STRIDE + ci] = 0;
    }
    __syncthreads();

    // ---- Phase 2: MFMA ----
    const int W    = tid >> 6;       // wave id -> co-tile
    const int lane = tid & 63;
    const int lm   = lane & 15;
    const int g    = lane >> 4;

    floatx4 acc[8];
    #pragma unroll
    for (int nt = 0; nt < 8; ++nt) acc[nt] = (floatx4){0.f, 0.f, 0.f, 0.f};

    const short* arow = Abf + (W * 16 + lm) * 320;

    for (int ks = 0; ks < 10; ++ks) {
        const int kbase = ks * 32 + g * 8;
        const int tap   = kbase >> 6;
        const int cib   = kbase & 63;

        short8 a = *(const short8*)(arow + kbase);
        #pragma unroll
        for (int nt = 0; nt < 8; ++nt) {
            int wp = nt * 16 + lm + tap;
            short8 b = *(const short8*)&xsT[wp * LDS_STRIDE + cib];
            acc[nt] = __builtin_amdgcn_mfma_f32_16x16x32_bf16(a, b, acc[nt], 0, 0, 0);
        }
    }
    __syncthreads();   // xsT dead; t3s aliases it

    // ---- Phase 3: epilogue to LDS ----
    // D[row=g*4+r][col=lm], co = W*16+g*4+r, w = nt*16+lm.
    // Bank check: addr/4 = co*132 + w; lanes: lm + g*528 -> lm + 16*(g&1) mod 32
    // -> 32 banks, 2 lanes each -> free.
    #pragma unroll
    for (int nt = 0; nt < 8; ++nt) {
        #pragma unroll
        for (int r = 0; r < 4; ++r) {
            int co = W * 16 + g * 4 + r;
            t3s[co * T3_STRIDE + nt * 16 + lm] = acc[nt][r];
        }
    }
    __syncthreads();

    // ---- Phase 4: combine, 4 outputs/thread, 8 iterations ----
    float* orow = out + (((size_t)n * CC) * HH + h) * WW;   // + c*HH*WW + w
    #pragma unroll
    for (int it = 0; it < 8; ++it) {
        const int item = it * 256 + tid;
        const int flat = item * 4;          // c*128 + w0
        const int w0   = flat & (WW - 1);
        const int c    = flat >> 7;
        const float* xb = x + ((size_t)(n * CC + c) * HH) * WW;

        float win[3][12];
        #pragma unroll
        for (int r = 0; r < 3; ++r) {
            int hh = h + r - 1;
            bool hok = (unsigned)hh < HH;
            #pragma unroll
            for (int q = 0; q < 3; ++q) {
                int cb = w0 - 4 + q * 4;
                float4 v = make_float4(0.f, 0.f, 0.f, 0.f);
                if (hok && (unsigned)cb < WW)
                    v = *(const float4*)(xb + hh * WW + cb);
                win[r][q * 4 + 0] = v.x; win[r][q * 4 + 1] = v.y;
                win[r][q * 4 + 2] = v.z; win[r][q * 4 + 3] = v.w;
            }
        }
        // w==0 wrap: rhs cols 125, 127 (j=2 -> col 129 -> 0 via pad).
        float wrap0[3] = {0.f, 0.f, 0.f}, wrap1[3] = {0.f, 0.f, 0.f};
        if (w0 == 0) {
            #pragma unroll
            for (int r = 0; r < 3; ++r) {
                int hh = h + r - 1;
                if ((unsigned)hh < HH) {
                    wrap0[r] = xb[hh * WW + 125];
                    wrap1[r] = xb[hh * WW + 127];
                }
            }
        }
        float wc[9];
        #pragma unroll
        for (int t = 0; t < 9; ++t) wc[t] = w7[c * 9 + t];

        float4 t3v = *(const float4*)&t3s[c * T3_STRIDE + w0];
        float res[4];
        #pragma unroll
        for (int e = 0; e < 4; ++e) {
            float a = 0.f;
            #pragma unroll
            for (int j = 0; j < 3; ++j) {
                #pragma unroll
                for (int i = 0; i < 3; ++i) {
                    float lhs = win[1][e + 2 * i + 2];        // col w+2(i-1)
                    float rhs;
                    if (e == 0 && w0 == 0)
                        rhs = (j == 0) ? wrap0[i] : ((j == 1) ? wrap1[i] : 0.f);
                    else
                        rhs = win[i][e + 2 * j + 1];          // col w+2j-3
                    a = fmaf(wc[j * 3 + i], fmaxf(lhs, rhs), a);
                }
            }
            res[e] = a;
        }
        float4 o;
        o.x = res[0] * t3v.x; o.y = res[1] * t3v.y;
        o.z = res[2] * t3v.z; o.w = res[3] * t3v.w;
        *(float4*)(orow + (size_t)c * (HH * WW) + w0) = o;
    }
}

extern "C" void kernel_launch(void* const* d_in, const int* in_sizes, int n_in,
                              void* d_out, int out_size, void* d_ws, size_t ws_size,
                              hipStream_t stream) {
    const float* x  = (const float*)d_in[0];
    const float* w3 = (const float*)d_in[1];
    const float* w7 = (const float*)d_in[2];
    float* out = (float*)d_out;

    short* Abf = (short*)d_ws;   // 40 KiB bf16 weights

    prep_w<<<(CC * CC * 5 + 255) / 256, 256, 0, stream>>>(w3, Abf);
    fused<<<NN * HH, 256, 0, stream>>>(x, Abf, w7, out);
}